// Round 1
// baseline (415.738 us; speedup 1.0000x reference)
//
#include <hip/hip_runtime.h>
#include <hip/hip_bf16.h>

// MHA forward: B=4,T=1024,D=2048,H=16,E=128 causal + key-padding mask.
// Pipeline (all bf16 MFMA, f32 accum):
//  1) cast x,Wq,Wk,Wv,Wo -> bf16 in ws; concat biases
//  2) GEMM1: QKV[4096,6144] = x[4096,2048] @ Wqkv[6144,2048]^T + b
//  3) transpose V -> Vt[B,H,E,T]
//  4) flash attention (causal+mask) -> Y[4096,2048] (head-concat layout)
//  5) GEMM2: out[4096,2048] = Y @ Wo^T + bo (f32)
// ws layout (bytes):                                total 100,687,872
//   wqkv  @0         25165824   (aliased by Vt 16777216 after GEMM1)
//   xbf   @25165824  16777216   (aliased by Y after GEMM1)
//   qkv   @41943040  50331648
//   wobf  @92274688   8388608
//   bqkv  @100663296    24576

typedef __attribute__((ext_vector_type(4))) float f32x4;
typedef __attribute__((ext_vector_type(8))) short s16x8;
typedef __attribute__((ext_vector_type(4))) unsigned short us16x4;
typedef __attribute__((ext_vector_type(8))) unsigned short us16x8;

#define Bd 4
#define Td 1024
#define Dd 2048
#define Hd 16
#define Ed 128

__device__ __forceinline__ unsigned short f2bf(float f) {
  unsigned int u = __builtin_bit_cast(unsigned int, f);
  u = (u + 0x7fffu + ((u >> 16) & 1u)) >> 16;  // RNE
  return (unsigned short)u;
}

__device__ __forceinline__ void gload_lds16(const void* g, void* l) {
  __builtin_amdgcn_global_load_lds(
      (const __attribute__((address_space(1))) unsigned int*)g,
      (__attribute__((address_space(3))) unsigned int*)l, 16, 0, 0);
}

// ---------------- casts ----------------
__global__ void cvt_f32_bf16(const float* __restrict__ in,
                             unsigned short* __restrict__ out, int n4) {
  int i = blockIdx.x * 256 + threadIdx.x;
  if (i >= n4) return;
  float4 v = reinterpret_cast<const float4*>(in)[i];
  us16x4 o = {f2bf(v.x), f2bf(v.y), f2bf(v.z), f2bf(v.w)};
  reinterpret_cast<us16x4*>(out)[i] = o;
}

__global__ void bias_concat(const float* __restrict__ bq, const float* __restrict__ bk,
                            const float* __restrict__ bv, float* __restrict__ out) {
  int i = blockIdx.x * 256 + threadIdx.x;  // 0..6143
  const float* s = (i < 2048) ? bq : ((i < 4096) ? bk : bv);
  out[i] = s[i & 2047];
}

// ---------------- GEMM: C[M,N] = A[M,K] * Bm[N,K]^T + bias ----------------
// 128x128 tile, BK=64, 4 waves (2x2), 16x16x32 bf16 MFMA.
// LDS: row-major [128][64] bf16 with slot-XOR swizzle (slot ^= row&7, 16B slots):
// staging keeps LDS linear + pre-swizzles the per-lane GLOBAL source (rule 21);
// ds_read applies the same XOR -> conflict-free b128 reads, 128B-coalesced loads.
template <int OUT_BF16>
__global__ __launch_bounds__(256, 2) void gemm_bt(
    const unsigned short* __restrict__ A, const unsigned short* __restrict__ Bm,
    const float* __restrict__ bias, void* __restrict__ C, int M, int N, int K) {
  __shared__ unsigned short As[8192];
  __shared__ unsigned short Bs[8192];
  const int tid = threadIdx.x;
  const int lane = tid & 63, w = tid >> 6;
  const int g = lane >> 4, m15 = lane & 15;
  const int wr = w >> 1, wc = w & 1;
  const int row0 = blockIdx.y * 128, col0 = blockIdx.x * 128;

  f32x4 acc[4][4] = {};
  const int nK = K >> 6;
  for (int kt = 0; kt < nK; ++kt) {
    const int k0 = kt << 6;
    __syncthreads();
#pragma unroll
    for (int i = 0; i < 4; ++i) {
      const int p = w * 256 + i * 64 + lane;  // phys 16B-chunk id [0,1024)
      const int prow = p >> 3;
      const int lslot = (p & 7) ^ (prow & 7);
      gload_lds16(A + (size_t)(row0 + prow) * K + k0 + lslot * 8,
                  &As[(size_t)(w * 256 + i * 64) * 8]);
      gload_lds16(Bm + (size_t)(col0 + prow) * K + k0 + lslot * 8,
                  &Bs[(size_t)(w * 256 + i * 64) * 8]);
    }
    __syncthreads();
#pragma unroll
    for (int ks = 0; ks < 2; ++ks) {
      s16x8 af[4], bf[4];
#pragma unroll
      for (int i = 0; i < 4; ++i) {
        const int r = wr * 64 + i * 16 + m15;
        af[i] = *reinterpret_cast<const s16x8*>(&As[(r * 8 + ((ks * 4 + g) ^ (r & 7))) * 8]);
      }
#pragma unroll
      for (int j = 0; j < 4; ++j) {
        const int r = wc * 64 + j * 16 + m15;
        bf[j] = *reinterpret_cast<const s16x8*>(&Bs[(r * 8 + ((ks * 4 + g) ^ (r & 7))) * 8]);
      }
#pragma unroll
      for (int i = 0; i < 4; ++i)
#pragma unroll
        for (int j = 0; j < 4; ++j)
          acc[i][j] = __builtin_amdgcn_mfma_f32_16x16x32_bf16(af[i], bf[j], acc[i][j], 0, 0, 0);
    }
  }
#pragma unroll
  for (int j = 0; j < 4; ++j) {
    const int col = col0 + wc * 64 + j * 16 + m15;
    const float bv = bias[col];
#pragma unroll
    for (int i = 0; i < 4; ++i)
#pragma unroll
      for (int r = 0; r < 4; ++r) {
        const int row = row0 + wr * 64 + i * 16 + g * 4 + r;
        const float v = acc[i][j][r] + bv;
        if (OUT_BF16)
          ((unsigned short*)C)[(size_t)row * N + col] = f2bf(v);
        else
          ((float*)C)[(size_t)row * N + col] = v;
      }
  }
}

// ---------------- V transpose: QKV V-part -> Vt[bh][e][t] ----------------
__global__ void transpose_v(const unsigned short* __restrict__ QKV,
                            unsigned short* __restrict__ Vt) {
  const int bh = blockIdx.y;
  const int t0 = blockIdx.x * 64;
  const int b = bh >> 4, h = bh & 15;
  const int tid = threadIdx.x;
  const unsigned short* src = QKV + (size_t)(b * Td) * 6144 + 4096 + h * 128;
  unsigned short* dst = Vt + (size_t)bh * 128 * Td;
#pragma unroll
  for (int kk = 0; kk < 4; ++kk) {
    const int c = tid + kk * 256;  // 0..1023
    const int e = c >> 3, tc = c & 7;
    us16x8 v;
#pragma unroll
    for (int j = 0; j < 8; ++j)
      v[j] = src[(size_t)(t0 + tc * 8 + j) * 6144 + e];
    *reinterpret_cast<us16x8*>(&dst[(size_t)e * Td + t0 + tc * 8]) = v;
  }
}

// ---------------- flash attention ----------------
// grid (8, 64): x = q-tile (128 rows), y = b*H+h. 4 waves x 32 q-rows.
// KVBLK=32. K LDS [32][128] row&7-swizzled; V LDS [128][32] (from Vt) e&3-swizzled.
__global__ __launch_bounds__(256, 2) void attn(
    const unsigned short* __restrict__ QKV, const unsigned short* __restrict__ Vt,
    const int* __restrict__ amask, unsigned short* __restrict__ Y) {
  __shared__ unsigned short Ks[4096];
  __shared__ unsigned short Vs[4096];
  __shared__ unsigned short Ps[4096];  // 4 waves x [32][32]
  const int qt = blockIdx.x, bh = blockIdx.y;
  const int b = bh >> 4, h = bh & 15;
  const int q0 = qt * 128;
  const int tid = threadIdx.x, lane = tid & 63, w = tid >> 6;
  const int g = lane >> 4, m15 = lane & 15;
  const float scale = 0.08838834764831845f;  // 1/sqrt(128)

  s16x8 qf[2][4];
#pragma unroll
  for (int qr = 0; qr < 2; ++qr)
#pragma unroll
    for (int c = 0; c < 4; ++c)
      qf[qr][c] = *reinterpret_cast<const s16x8*>(
          &QKV[(size_t)(b * Td + q0 + w * 32 + qr * 16 + m15) * 6144 + h * 128 + c * 32 + g * 8]);

  f32x4 yacc[2][8] = {};
  float mrow[2][4], lrow[2][4];
#pragma unroll
  for (int qr = 0; qr < 2; ++qr)
#pragma unroll
    for (int r = 0; r < 4; ++r) { mrow[qr][r] = -1e30f; lrow[qr][r] = 0.f; }

  const int nkt = (q0 + 128) >> 5;
  for (int kt = 0; kt < nkt; ++kt) {
    const int k0 = kt << 5;
    __syncthreads();
#pragma unroll
    for (int i = 0; i < 2; ++i) {
      const int p = w * 128 + i * 64 + lane;  // [0,512)
      {  // K: rows 0..31 (k), 16 slots (e)
        const int prow = p >> 4;
        const int lslot = (p & 15) ^ (prow & 7);
        gload_lds16(QKV + (size_t)(b * Td + k0 + prow) * 6144 + 2048 + h * 128 + lslot * 8,
                    &Ks[(size_t)(w * 128 + i * 64) * 8]);
      }
      {  // V: rows 0..127 (e), 4 slots (k)
        const int e = p >> 2;
        const int lslot = (p & 3) ^ (e & 3);
        gload_lds16(Vt + (size_t)(bh * 128 + e) * Td + k0 + lslot * 8,
                    &Vs[(size_t)(w * 128 + i * 64) * 8]);
      }
    }
    __syncthreads();

    // S = Q K^T (per wave: 32q x 32k)
    f32x4 sf[2][2] = {};
#pragma unroll
    for (int kc = 0; kc < 2; ++kc)
#pragma unroll
      for (int c = 0; c < 4; ++c) {
        const int krow = kc * 16 + m15;
        const s16x8 kf = *reinterpret_cast<const s16x8*>(
            &Ks[(krow * 16 + ((c * 4 + g) ^ (krow & 7))) * 8]);
#pragma unroll
        for (int qr = 0; qr < 2; ++qr)
          sf[qr][kc] = __builtin_amdgcn_mfma_f32_16x16x32_bf16(qf[qr][c], kf, sf[qr][kc], 0, 0, 0);
      }

    // scale + causal + key mask
#pragma unroll
    for (int kc = 0; kc < 2; ++kc) {
      const int kgl = k0 + kc * 16 + m15;
      const int amv = amask[b * Td + kgl];
#pragma unroll
      for (int qr = 0; qr < 2; ++qr)
#pragma unroll
        for (int r = 0; r < 4; ++r) {
          const int qg = q0 + w * 32 + qr * 16 + g * 4 + r;
          const float s = sf[qr][kc][r] * scale;
          sf[qr][kc][r] = (kgl <= qg && amv != 0) ? s : -1e30f;
        }
    }

    // online softmax (rows live in 16-lane groups; xor-shuffle reduce)
#pragma unroll
    for (int qr = 0; qr < 2; ++qr) {
      float al[4];
#pragma unroll
      for (int r = 0; r < 4; ++r) {
        float t = fmaxf(sf[qr][0][r], sf[qr][1][r]);
        t = fmaxf(t, __shfl_xor(t, 1));
        t = fmaxf(t, __shfl_xor(t, 2));
        t = fmaxf(t, __shfl_xor(t, 4));
        t = fmaxf(t, __shfl_xor(t, 8));
        const float mn = fmaxf(mrow[qr][r], t);
        al[r] = __expf(mrow[qr][r] - mn);
        mrow[qr][r] = mn;
        const float p0 = __expf(sf[qr][0][r] - mn);
        const float p1 = __expf(sf[qr][1][r] - mn);
        sf[qr][0][r] = p0;
        sf[qr][1][r] = p1;
        float rs = p0 + p1;
        rs += __shfl_xor(rs, 1);
        rs += __shfl_xor(rs, 2);
        rs += __shfl_xor(rs, 4);
        rs += __shfl_xor(rs, 8);
        lrow[qr][r] = lrow[qr][r] * al[r] + rs;
      }
#pragma unroll
      for (int n = 0; n < 8; ++n)
#pragma unroll
        for (int r = 0; r < 4; ++r) yacc[qr][n][r] *= al[r];
    }

    // P -> LDS (per-wave region), reread as A-frags
    unsigned short* pw = &Ps[w * 1024];
#pragma unroll
    for (int qr = 0; qr < 2; ++qr)
#pragma unroll
      for (int kc = 0; kc < 2; ++kc) {
        const int kc3 = kc * 2 + (m15 >> 3), j = m15 & 7;
#pragma unroll
        for (int r = 0; r < 4; ++r)
          pw[(kc3 * 32 + qr * 16 + g * 4 + r) * 8 + j] = f2bf(sf[qr][kc][r]);
      }
    asm volatile("s_waitcnt lgkmcnt(0)" ::: "memory");
    __builtin_amdgcn_sched_barrier(0);
    s16x8 pf[2];
#pragma unroll
    for (int qr = 0; qr < 2; ++qr)
      pf[qr] = *reinterpret_cast<const s16x8*>(&pw[(g * 32 + qr * 16 + m15) * 8]);

#pragma unroll
    for (int n = 0; n < 8; ++n) {
      const int e = n * 16 + m15;
      const s16x8 vf = *reinterpret_cast<const s16x8*>(&Vs[(e * 4 + (g ^ (e & 3))) * 8]);
      yacc[0][n] = __builtin_amdgcn_mfma_f32_16x16x32_bf16(pf[0], vf, yacc[0][n], 0, 0, 0);
      yacc[1][n] = __builtin_amdgcn_mfma_f32_16x16x32_bf16(pf[1], vf, yacc[1][n], 0, 0, 0);
    }
  }

  // epilogue: y / l -> Y[b,t,h,e] bf16
#pragma unroll
  for (int qr = 0; qr < 2; ++qr)
#pragma unroll
    for (int r = 0; r < 4; ++r) {
      const float inv = 1.0f / lrow[qr][r];
      const size_t rowoff = (size_t)(b * Td + q0 + w * 32 + qr * 16 + g * 4 + r) * Dd + h * Ed;
#pragma unroll
      for (int n = 0; n < 8; ++n)
        Y[rowoff + n * 16 + m15] = f2bf(yacc[qr][n][r] * inv);
    }
}

extern "C" void kernel_launch(void* const* d_in, const int* in_sizes, int n_in,
                              void* d_out, int out_size, void* d_ws, size_t ws_size,
                              hipStream_t stream) {
  const float* x = (const float*)d_in[0];
  const int* amask = (const int*)d_in[1];
  const float* Wq = (const float*)d_in[2];
  const float* bq = (const float*)d_in[3];
  const float* Wk = (const float*)d_in[4];
  const float* bk = (const float*)d_in[5];
  const float* Wv = (const float*)d_in[6];
  const float* bv = (const float*)d_in[7];
  const float* Wo = (const float*)d_in[8];
  const float* bo = (const float*)d_in[9];
  float* out = (float*)d_out;

  char* ws = (char*)d_ws;
  unsigned short* wqkv = (unsigned short*)(ws);                        // 25165824 B
  unsigned short* xbf  = (unsigned short*)(ws + 25165824);             // 16777216 B
  unsigned short* qkv  = (unsigned short*)(ws + 41943040);             // 50331648 B
  unsigned short* wobf = (unsigned short*)(ws + 92274688);             //  8388608 B
  float* bqkv          = (float*)(ws + 100663296);                     //    24576 B
  unsigned short* vt   = wqkv;  // alias: weights dead after GEMM1
  unsigned short* ybuf = xbf;   // alias: x_bf16 dead after GEMM1

  cvt_f32_bf16<<<8192, 256, 0, stream>>>(x, xbf, 2097152);
  cvt_f32_bf16<<<4096, 256, 0, stream>>>(Wq, wqkv, 1048576);
  cvt_f32_bf16<<<4096, 256, 0, stream>>>(Wk, wqkv + 4194304, 1048576);
  cvt_f32_bf16<<<4096, 256, 0, stream>>>(Wv, wqkv + 8388608, 1048576);
  cvt_f32_bf16<<<4096, 256, 0, stream>>>(Wo, wobf, 1048576);
  bias_concat<<<24, 256, 0, stream>>>(bq, bk, bv, bqkv);

  gemm_bt<1><<<dim3(48, 32), 256, 0, stream>>>(xbf, wqkv, bqkv, (void*)qkv, 4096, 6144, 2048);
  transpose_v<<<dim3(16, 64), 256, 0, stream>>>(qkv, vt);
  attn<<<dim3(8, 64), 256, 0, stream>>>(qkv, vt, amask, ybuf);
  gemm_bt<0><<<dim3(16, 32), 256, 0, stream>>>(ybuf, wobf, bo, (void*)out, 4096, 2048, 2048);
}

// Round 2
// 409.831 us; speedup vs baseline: 1.0144x; 1.0144x over previous
//
#include <hip/hip_runtime.h>
#include <hip/hip_bf16.h>

// MHA forward: B=4,T=1024,D=2048,H=16,E=128 causal + key-padding mask.
//  1) cast x,Wq,Wk,Wv,Wo -> bf16; concat biases
//  2) GEMM1: [4096,6144] = x @ Wqkv^T + b; Q,K -> qk[4096,4096] bf16,
//     V written TRANSPOSED to vt[bh][e][t] in the epilogue (no transpose pass)
//  3) flash attention, paired causal tiles (balanced 17 group-iters/block),
//     KVBLK=64, 2-phase staged LDS, swizzled K/V/P -> Y[4096,2048] bf16
//  4) GEMM2: out = Y @ Wo^T + bo (f32)
// ws layout (bytes):                      total 100,687,872
//   wqkv @0         25165824
//   xbf  @25165824  16777216  (aliased by Y after GEMM1)
//   qk   @41943040  33554432
//   vt   @75497472  16777216
//   wobf @92274688   8388608
//   bqkv @100663296    24576

typedef __attribute__((ext_vector_type(4))) float f32x4;
typedef __attribute__((ext_vector_type(8))) short s16x8;
typedef __attribute__((ext_vector_type(4))) unsigned short us16x4;

#define Td 1024
#define Dd 2048

__device__ __forceinline__ unsigned short f2bf(float f) {
  unsigned int u = __builtin_bit_cast(unsigned int, f);
  u = (u + 0x7fffu + ((u >> 16) & 1u)) >> 16;  // RNE
  return (unsigned short)u;
}

__device__ __forceinline__ void gload_lds16(const void* g, void* l) {
  __builtin_amdgcn_global_load_lds(
      (const __attribute__((address_space(1))) unsigned int*)g,
      (__attribute__((address_space(3))) unsigned int*)l, 16, 0, 0);
}

// ---------------- casts ----------------
__global__ void cvt_f32_bf16(const float* __restrict__ in,
                             unsigned short* __restrict__ out, int n4) {
  int i = blockIdx.x * 256 + threadIdx.x;
  if (i >= n4) return;
  float4 v = reinterpret_cast<const float4*>(in)[i];
  us16x4 o = {f2bf(v.x), f2bf(v.y), f2bf(v.z), f2bf(v.w)};
  reinterpret_cast<us16x4*>(out)[i] = o;
}

__global__ void bias_concat(const float* __restrict__ bq, const float* __restrict__ bk,
                            const float* __restrict__ bv, float* __restrict__ out) {
  int i = blockIdx.x * 256 + threadIdx.x;  // 0..6143
  const float* s = (i < 2048) ? bq : ((i < 4096) ? bk : bv);
  out[i] = s[i & 2047];
}

// ---------------- GEMM: C = A[M,K] * Bm[N,K]^T + bias ----------------
// 128x128 tile, BK=64, 4 waves (2x2), 16x16x32 bf16 MFMA.
// MODE 0: f32 C (ldc stride). MODE 1: QKV — cols<4096 -> bf16 qk (ldc=4096);
// cols>=4096 -> V transposed into Cv[bh][e][t] (packed 4-row 8B stores).
template <int MODE>
__global__ __launch_bounds__(256, 2) void gemm_bt(
    const unsigned short* __restrict__ A, const unsigned short* __restrict__ Bm,
    const float* __restrict__ bias, void* __restrict__ C,
    unsigned short* __restrict__ Cv, int M, int N, int K, int ldc) {
  __shared__ unsigned short As[8192];
  __shared__ unsigned short Bs[8192];
  const int tid = threadIdx.x;
  const int lane = tid & 63, w = tid >> 6;
  const int g = lane >> 4, m15 = lane & 15;
  const int wr = w >> 1, wc = w & 1;
  const int row0 = blockIdx.y * 128, col0 = blockIdx.x * 128;

  f32x4 acc[4][4] = {};
  const int nK = K >> 6;
  for (int kt = 0; kt < nK; ++kt) {
    const int k0 = kt << 6;
    __syncthreads();
#pragma unroll
    for (int i = 0; i < 4; ++i) {
      const int p = w * 256 + i * 64 + lane;  // phys 16B-chunk id [0,1024)
      const int prow = p >> 3;
      const int lslot = (p & 7) ^ (prow & 7);
      gload_lds16(A + (size_t)(row0 + prow) * K + k0 + lslot * 8,
                  &As[(size_t)(w * 256 + i * 64) * 8]);
      gload_lds16(Bm + (size_t)(col0 + prow) * K + k0 + lslot * 8,
                  &Bs[(size_t)(w * 256 + i * 64) * 8]);
    }
    __syncthreads();
#pragma unroll
    for (int ks = 0; ks < 2; ++ks) {
      s16x8 af[4], bf[4];
#pragma unroll
      for (int i = 0; i < 4; ++i) {
        const int r = wr * 64 + i * 16 + m15;
        af[i] = *reinterpret_cast<const s16x8*>(&As[(r * 8 + ((ks * 4 + g) ^ (r & 7))) * 8]);
      }
#pragma unroll
      for (int j = 0; j < 4; ++j) {
        const int r = wc * 64 + j * 16 + m15;
        bf[j] = *reinterpret_cast<const s16x8*>(&Bs[(r * 8 + ((ks * 4 + g) ^ (r & 7))) * 8]);
      }
#pragma unroll
      for (int i = 0; i < 4; ++i)
#pragma unroll
        for (int j = 0; j < 4; ++j)
          acc[i][j] = __builtin_amdgcn_mfma_f32_16x16x32_bf16(af[i], bf[j], acc[i][j], 0, 0, 0);
    }
  }
  if (MODE == 1 && col0 >= 4096) {
    const int vc0 = col0 - 4096;
#pragma unroll
    for (int j = 0; j < 4; ++j) {
      const int vcol = vc0 + wc * 64 + j * 16 + m15;
      const float bv = bias[4096 + vcol];
      const int hh = vcol >> 7, e = vcol & 127;
#pragma unroll
      for (int i = 0; i < 4; ++i) {
        const int row = row0 + wr * 64 + i * 16 + g * 4;
        const int bb = row >> 10, tt = row & 1023;
        us16x4 pk;
#pragma unroll
        for (int r = 0; r < 4; ++r) pk[r] = f2bf(acc[i][j][r] + bv);
        *reinterpret_cast<us16x4*>(&Cv[((size_t)((bb * 16 + hh) * 128 + e)) * Td + tt]) = pk;
      }
    }
  } else {
#pragma unroll
    for (int j = 0; j < 4; ++j) {
      const int col = col0 + wc * 64 + j * 16 + m15;
      const float bv = bias[col];
#pragma unroll
      for (int i = 0; i < 4; ++i)
#pragma unroll
        for (int r = 0; r < 4; ++r) {
          const int row = row0 + wr * 64 + i * 16 + g * 4 + r;
          const float v = acc[i][j][r] + bv;
          if (MODE)
            ((unsigned short*)C)[(size_t)row * ldc + col] = f2bf(v);
          else
            ((float*)C)[(size_t)row * ldc + col] = v;
        }
    }
  }
}

// ---------------- flash attention (paired causal tiles) ----------------
// 16 q-tiles of 64 rows; block p handles tiles {p, 15-p} -> 17 group-iters
// for every block. 4 waves; wave w: rows ta*64+w*16 (A) and tb*64+w*16 (B).
// KVBLK=64, double-buffered K/V LDS, 2-phase (stage next || compute cur).
#define SCALE 0.08838834764831845f

#define GRP_SOFTMAX(SF, G, QB)                                                 \
  {                                                                            \
    _Pragma("unroll") for (int kc = 0; kc < 4; ++kc) {                         \
      const int kgl = k0 + kc * 16 + m15;                                      \
      const int okm = am[kc];                                                  \
      _Pragma("unroll") for (int r = 0; r < 4; ++r) {                          \
        const int qg = (QB) + g * 4 + r;                                       \
        SF[kc][r] = (okm && kgl <= qg) ? SF[kc][r] * SCALE : -3.0e38f;         \
      }                                                                        \
    }                                                                          \
    _Pragma("unroll") for (int r = 0; r < 4; ++r) {                            \
      float t = fmaxf(fmaxf(SF[0][r], SF[1][r]), fmaxf(SF[2][r], SF[3][r]));   \
      t = fmaxf(t, __shfl_xor(t, 1));                                          \
      t = fmaxf(t, __shfl_xor(t, 2));                                          \
      t = fmaxf(t, __shfl_xor(t, 4));                                          \
      t = fmaxf(t, __shfl_xor(t, 8));                                          \
      const float mn = fmaxf(mrow[G][r], t);                                   \
      const float al = __expf(mrow[G][r] - mn);                                \
      mrow[G][r] = mn;                                                         \
      float rs = 0.f;                                                          \
      _Pragma("unroll") for (int kc = 0; kc < 4; ++kc) {                       \
        SF[kc][r] = __expf(SF[kc][r] - mn);                                    \
        rs += SF[kc][r];                                                       \
      }                                                                        \
      rs += __shfl_xor(rs, 1);                                                 \
      rs += __shfl_xor(rs, 2);                                                 \
      rs += __shfl_xor(rs, 4);                                                 \
      rs += __shfl_xor(rs, 8);                                                 \
      lrow[G][r] = lrow[G][r] * al + rs;                                       \
      _Pragma("unroll") for (int n = 0; n < 8; ++n) yacc[G][n][r] *= al;       \
    }                                                                          \
    _Pragma("unroll") for (int kc = 0; kc < 4; ++kc)                           \
        _Pragma("unroll") for (int r = 0; r < 4; ++r) {                        \
      const int prow = (G) * 16 + g * 4 + r;                                   \
      pw[prow * 64 + ((kc * 16 + m15) ^ ((prow & 7) << 3))] = f2bf(SF[kc][r]); \
    }                                                                          \
  }

__global__ __launch_bounds__(256, 2) void attn(
    const unsigned short* __restrict__ qk, const unsigned short* __restrict__ vt,
    const int* __restrict__ amask, unsigned short* __restrict__ Y) {
  __shared__ unsigned short Ks[2][8192];  // [64 k][16 slot16] swizzled
  __shared__ unsigned short Vs[2][8192];  // [128 e][8 slot16] swizzled
  __shared__ unsigned short Ps[4][2048];  // per-wave [32 q][64 k] swizzled
  const int d = blockIdx.y * 8 + blockIdx.x;
  const int wk = (d & 7) * 64 + (d >> 3);  // XCD-contiguous bh groups
  const int p = wk & 7, bh = wk >> 3;
  const int b = bh >> 4, h = bh & 15;
  const int ta = p, tb = 15 - p;
  const int tid = threadIdx.x, lane = tid & 63, w = tid >> 6;
  const int g = lane >> 4, m15 = lane & 15;
  const int qab = ta * 64 + w * 16, qbb = tb * 64 + w * 16;
  unsigned short* pw = Ps[w];

  s16x8 qf[2][4];
#pragma unroll
  for (int G = 0; G < 2; ++G) {
    const int qb_ = G ? qbb : qab;
#pragma unroll
    for (int c = 0; c < 4; ++c)
      qf[G][c] = *reinterpret_cast<const s16x8*>(
          &qk[(size_t)(b * Td + qb_ + m15) * 4096 + h * 128 + c * 32 + g * 8]);
  }

  f32x4 yacc[2][8] = {};
  float mrow[2][4], lrow[2][4];
#pragma unroll
  for (int G = 0; G < 2; ++G)
#pragma unroll
    for (int r = 0; r < 4; ++r) { mrow[G][r] = -3.0e38f; lrow[G][r] = 0.f; }

  auto stage = [&](int buf, int kt) {
    const int k0s = kt << 6;
#pragma unroll
    for (int i = 0; i < 4; ++i) {
      const int pc = i * 256 + tid;  // K chunk [0,1024)
      const int krow = pc >> 4;
      const int ls = (pc & 15) ^ (krow & 7);
      gload_lds16(qk + (size_t)(b * Td + k0s + krow) * 4096 + 2048 + h * 128 + ls * 8,
                  &Ks[buf][(size_t)(i * 256 + w * 64) * 8]);
      const int e = pc >> 3;
      const int lv = (pc & 7) ^ (e & 7);
      gload_lds16(vt + (size_t)(bh * 128 + e) * Td + k0s + lv * 8,
                  &Vs[buf][(size_t)(i * 256 + w * 64) * 8]);
    }
  };

  const int nkt = tb + 1;
  stage(0, 0);
  asm volatile("s_waitcnt vmcnt(0)" ::: "memory");
  __syncthreads();
  int cur = 0;
  for (int kt = 0; kt < nkt; ++kt) {
    const int k0 = kt << 6;
    const bool actA = (kt <= ta);
    if (kt + 1 < nkt) stage(cur ^ 1, kt + 1);
    int am[4];
#pragma unroll
    for (int kc = 0; kc < 4; ++kc) am[kc] = amask[b * Td + k0 + kc * 16 + m15];

    // S = Q K^T
    f32x4 sf0[4] = {}, sf1[4] = {};
    __builtin_amdgcn_s_setprio(1);
#pragma unroll
    for (int kc = 0; kc < 4; ++kc) {
      const int krow = kc * 16 + m15;
#pragma unroll
      for (int c = 0; c < 4; ++c) {
        const s16x8 kf = *reinterpret_cast<const s16x8*>(
            &Ks[cur][(krow * 16 + ((c * 4 + g) ^ (krow & 7))) * 8]);
        if (actA) sf0[kc] = __builtin_amdgcn_mfma_f32_16x16x32_bf16(qf[0][c], kf, sf0[kc], 0, 0, 0);
        sf1[kc] = __builtin_amdgcn_mfma_f32_16x16x32_bf16(qf[1][c], kf, sf1[kc], 0, 0, 0);
      }
    }
    __builtin_amdgcn_s_setprio(0);

    if (actA) GRP_SOFTMAX(sf0, 0, qab)
    GRP_SOFTMAX(sf1, 1, qbb)

    asm volatile("s_waitcnt lgkmcnt(0)" ::: "memory");
    __builtin_amdgcn_sched_barrier(0);
    s16x8 pa0[2], pa1[2];
    if (actA) {
#pragma unroll
      for (int kcc = 0; kcc < 2; ++kcc)
        pa0[kcc] = *reinterpret_cast<const s16x8*>(
            &pw[m15 * 64 + ((kcc * 32 + g * 8) ^ ((m15 & 7) << 3))]);
    }
#pragma unroll
    for (int kcc = 0; kcc < 2; ++kcc) {
      const int prow = 16 + m15;
      pa1[kcc] = *reinterpret_cast<const s16x8*>(
          &pw[prow * 64 + ((kcc * 32 + g * 8) ^ ((prow & 7) << 3))]);
    }

    __builtin_amdgcn_s_setprio(1);
#pragma unroll
    for (int n = 0; n < 8; ++n) {
      const int e = n * 16 + m15;
#pragma unroll
      for (int kcc = 0; kcc < 2; ++kcc) {
        const s16x8 vf = *reinterpret_cast<const s16x8*>(
            &Vs[cur][(e * 8 + ((kcc * 4 + g) ^ (e & 7))) * 8]);
        if (actA) yacc[0][n] = __builtin_amdgcn_mfma_f32_16x16x32_bf16(pa0[kcc], vf, yacc[0][n], 0, 0, 0);
        yacc[1][n] = __builtin_amdgcn_mfma_f32_16x16x32_bf16(pa1[kcc], vf, yacc[1][n], 0, 0, 0);
      }
    }
    __builtin_amdgcn_s_setprio(0);

    asm volatile("s_waitcnt vmcnt(0)" ::: "memory");
    __syncthreads();
    cur ^= 1;
  }

  // epilogue: y / l -> Y[b,t,h*128+e] bf16
#pragma unroll
  for (int G = 0; G < 2; ++G) {
    const int qb_ = G ? qbb : qab;
#pragma unroll
    for (int r = 0; r < 4; ++r) {
      const float inv = 1.0f / lrow[G][r];
      const size_t rowoff = (size_t)(b * Td + qb_ + g * 4 + r) * Dd + h * 128;
#pragma unroll
      for (int n = 0; n < 8; ++n)
        Y[rowoff + n * 16 + m15] = f2bf(yacc[G][n][r] * inv);
    }
  }
}

extern "C" void kernel_launch(void* const* d_in, const int* in_sizes, int n_in,
                              void* d_out, int out_size, void* d_ws, size_t ws_size,
                              hipStream_t stream) {
  const float* x = (const float*)d_in[0];
  const int* amask = (const int*)d_in[1];
  const float* Wq = (const float*)d_in[2];
  const float* bq = (const float*)d_in[3];
  const float* Wk = (const float*)d_in[4];
  const float* bk = (const float*)d_in[5];
  const float* Wv = (const float*)d_in[6];
  const float* bv = (const float*)d_in[7];
  const float* Wo = (const float*)d_in[8];
  const float* bo = (const float*)d_in[9];
  float* out = (float*)d_out;

  char* ws = (char*)d_ws;
  unsigned short* wqkv = (unsigned short*)(ws);             // 25165824 B
  unsigned short* xbf  = (unsigned short*)(ws + 25165824);  // 16777216 B
  unsigned short* qk   = (unsigned short*)(ws + 41943040);  // 33554432 B
  unsigned short* vt   = (unsigned short*)(ws + 75497472);  // 16777216 B
  unsigned short* wobf = (unsigned short*)(ws + 92274688);  //  8388608 B
  float* bqkv          = (float*)(ws + 100663296);          //    24576 B
  unsigned short* ybuf = xbf;  // alias: x_bf16 dead after GEMM1

  cvt_f32_bf16<<<8192, 256, 0, stream>>>(x, xbf, 2097152);
  cvt_f32_bf16<<<4096, 256, 0, stream>>>(Wq, wqkv, 1048576);
  cvt_f32_bf16<<<4096, 256, 0, stream>>>(Wk, wqkv + 4194304, 1048576);
  cvt_f32_bf16<<<4096, 256, 0, stream>>>(Wv, wqkv + 8388608, 1048576);
  cvt_f32_bf16<<<4096, 256, 0, stream>>>(Wo, wobf, 1048576);
  bias_concat<<<24, 256, 0, stream>>>(bq, bk, bv, bqkv);

  gemm_bt<1><<<dim3(48, 32), 256, 0, stream>>>(xbf, wqkv, bqkv, (void*)qk, vt, 4096, 6144, 2048, 4096);
  attn<<<dim3(8, 64), 256, 0, stream>>>(qk, vt, amask, ybuf);
  gemm_bt<0><<<dim3(16, 32), 256, 0, stream>>>(ybuf, wobf, bo, (void*)out, nullptr, 4096, 2048, 2048, 2048);
}